// Round 7
// baseline (516.115 us; speedup 1.0000x reference)
//
#include <hip/hip_runtime.h>
#include <hip/hip_fp16.h>
#include <hip/hip_fp8.h>

#define B_ 256
#define V_ 1000
#define P_ 200
#define L_ 50
#define H_ 384
#define H3_ 1152
#define NW_ 10
#define OUT1_OFF 12800000
#define PD 8

typedef _Float16 half8 __attribute__((ext_vector_type(8)));
typedef _Float16 half4_t __attribute__((ext_vector_type(4)));
typedef float floatx4 __attribute__((ext_vector_type(4)));

// ---------------------------------------------------------------------------
// prep: fp8 pair-packed w_hh, f16 gi-GEMM operands, gate softmax, out1.
// whh8 pair layout, byte j = ((w*36+u)*64+l)*16 + p*8 + e:
//   F=2u+p; c=F/6; k=F%6; kc=(c&1)*6+k; s=c>>1;
//   row=(s>>1)*384+(s&1)*192+16w+(l&15); col=kc*32+(l>>4)*8+e
// One dwordx4 per lane = B-fragments F=2u (lo 8B) and F=2u+1 (hi 8B).
// ---------------------------------------------------------------------------
__global__ __launch_bounds__(256) void prep_kernel(
    const float* __restrict__ gate_emb, const float* __restrict__ prog_emb,
    const float* __restrict__ w_ih, const float* __restrict__ w_hh,
    const int* __restrict__ instr, const int* __restrict__ tacts,
    float* __restrict__ g01, unsigned char* __restrict__ whh8,
    _Float16* __restrict__ wih_h, _Float16* __restrict__ prog_h,
    float* __restrict__ out)
{
  const int stride = gridDim.x * blockDim.x;
  const int tid = blockIdx.x * blockDim.x + threadIdx.x;

  for (int i = tid; i < H3_*H_; i += stride) {
    const int e = i & 7;
    const int p = (i >> 3) & 1;
    const int l = (i >> 4) & 63;
    const int q = i >> 10;            // w*36 + u
    const int u = q % 36, w = q / 36;
    const int F = 2*u + p;
    const int c = F / 6, k = F - 6*c;
    const int kc = (c & 1)*6 + k;
    const int s = c >> 1;
    const int row = (s >> 1)*384 + (s & 1)*192 + 16*w + (l & 15);
    const int col = kc*32 + (l >> 4)*8 + e;
    __hip_fp8_e4m3 qv(w_hh[row*H_ + col]);
    whh8[i] = qv.__x;
  }
  for (int i = tid; i < H3_*224; i += stride) {
    int r = i / 224, c = i - r*224;
    wih_h[i] = (_Float16)(c < P_ ? w_ih[r*P_ + c] : 0.f);
  }
  for (int i = tid; i < V_*P_; i += stride) prog_h[i] = (_Float16)prog_emb[i];
  for (int i = tid; i < NW_*B_; i += stride) {
    int w = i / B_, b = i - w*B_;
    int word = instr[(1+w)*B_ + b];
    float e0 = gate_emb[word*2], e1 = gate_emb[word*2+1];
    float m = fmaxf(e0, e1);
    float a = __expf(e0-m), c = __expf(e1-m);
    float inv = 1.f/(a+c);
    g01[i*2] = a*inv; g01[i*2+1] = c*inv;
  }
  for (int i = tid; i < B_*L_; i += stride) {
    int b = i / L_, l = i - b*L_;
    out[OUT1_OFF + i] = (float)tacts[(1+l)*B_ + b];
  }
}

// ---------------------------------------------------------------------------
// gi_gemm: giv[v][n] = program_emb[v] @ w_ih.T + b_ih   (vocab-wide, once)
// ---------------------------------------------------------------------------
__global__ __launch_bounds__(256) void gi_gemm(
    const _Float16* __restrict__ prog_h, const _Float16* __restrict__ wih_h,
    const float* __restrict__ b_ih, float* __restrict__ giv)
{
  __shared__ _Float16 pA[16][232];
  const int tid = threadIdx.x;
  const int v0 = blockIdx.x * 16;
  const int n0 = blockIdx.y * 64;

  for (int i = tid; i < 16*224; i += 256) {
    int r = i / 224, c = i - r*224;
    int v = v0 + r;
    _Float16 val = (_Float16)0.f;
    if (v < V_ && c < P_) val = prog_h[v*P_ + c];
    pA[r][c] = val;
  }
  __syncthreads();

  const int wave = tid >> 6, lane = tid & 63;
  const int m = lane & 15, kg = lane >> 4;
  const int n_t = n0 + wave*16;
  floatx4 acc = {0.f, 0.f, 0.f, 0.f};
  #pragma unroll
  for (int ks = 0; ks < 7; ++ks) {
    const int kk = ks*32 + kg*8;
    half8 av = *(const half8*)&pA[m][kk];
    half8 bv = *(const half8*)&wih_h[(n_t + m)*224 + kk];
    acc = __builtin_amdgcn_mfma_f32_16x16x32_f16(av, bv, acc, 0, 0, 0);
  }
  const int nn = n_t + m;
  const float bias = b_ih[nn];
  #pragma unroll
  for (int r = 0; r < 4; ++r) {
    int mm = v0 + kg*4 + r;
    if (mm < V_) giv[(size_t)mm*H3_ + nn] = acc[r] + bias;
  }
}

// ---------------------------------------------------------------------------
// steps: GRU recurrence, 16 blocks x 768 threads (12 waves).
// Weights stream straight to VGPRs: per wave per step, 36 dwordx4 loads
// (pair-packed B-fragments), rotating 36-slot static register pipeline,
// prefetch depth PD, consumed directly by MFMA. No LDS for weights, no
// manual vmcnt. LDS = 6 KB fp8 h image; 2 raw barriers/step (lgkm only,
// weight prefetch survives). Last PD units of each step prefetch the next
// step's first PD units (same data, step-invariant stream).
// ---------------------------------------------------------------------------
__global__ __launch_bounds__(768, 1) void steps_kernel(
    const uint4* __restrict__ whh8p, const float* __restrict__ giv,
    const float* __restrict__ g01, const float* __restrict__ keys,
    const float* __restrict__ bhh, const int* __restrict__ instr,
    _Float16* __restrict__ hdump)
{
  __shared__ unsigned long long hA[768];   // fp8 h image [ks*64+lane]

  const int bid = blockIdx.x, b0 = bid*16, tid = threadIdx.x;
  const int w = tid >> 6, lane = tid & 63, m_ = lane & 15, kg = lane >> 4;
  const int c0 = 16*w + m_, c1 = 192 + 16*w + m_;

  const uint4* __restrict__ wbase = whh8p + (size_t)w*36*64 + lane;

  float hreg[2][4];
  float bb[6], gvv[4][6], g0r[4], g1r[4];
  int wdr[4];

  #pragma unroll
  for (int g = 0; g < 3; ++g) {
    bb[g*2]   = bhh[g*384 + c0];
    bb[g*2+1] = bhh[g*384 + c1];
  }

  // h0 = tile(scratch_keys[0], 3)
  const float h0a = keys[c0 & 127];
  const float h0b = keys[c1 & 127];
  #pragma unroll
  for (int r = 0; r < 4; ++r) { hreg[0][r] = h0a; hreg[1][r] = h0b; }

  // initial fp8 hA image
  #pragma unroll
  for (int half = 0; half < 2; ++half) {
    const int c = half ? c1 : c0;
    const int base = (c >> 5)*512 + ((c >> 3) & 3)*128 + (c & 7);
    #pragma unroll
    for (int r = 0; r < 4; ++r) {
      __hip_fp8_e4m3 q(hreg[half][r]);
      ((unsigned char*)hA)[base + (kg*4 + r)*8] = q.__x;
    }
  }

  // word-0 parameter loads
  {
    int4 wd4 = *(const int4*)&instr[(1+0)*B_ + b0 + kg*4];
    wdr[0] = wd4.x; wdr[1] = wd4.y; wdr[2] = wd4.z; wdr[3] = wd4.w;
    #pragma unroll
    for (int r = 0; r < 4; ++r) {
      float2 gg = *(const float2*)&g01[(size_t)(b0 + kg*4 + r)*2];
      g0r[r] = gg.x; g1r[r] = gg.y;
    }
    #pragma unroll
    for (int r = 0; r < 4; ++r) {
      const float* gp = giv + (size_t)wdr[r]*H3_;
      #pragma unroll
      for (int g = 0; g < 3; ++g) {
        gvv[r][g*2]   = gp[g*384 + c0];
        gvv[r][g*2+1] = gp[g*384 + c1];
      }
    }
  }

  // initial h dump, slot 0
  #pragma unroll
  for (int half = 0; half < 2; ++half) {
    const int c = half ? c1 : c0;
    half4_t hv;
    #pragma unroll
    for (int r = 0; r < 4; ++r) hv[r] = (_Float16)hreg[half][r];
    *(half4_t*)&hdump[(((size_t)0*16 + bid)*384 + c)*16 + kg*4] = hv;
  }

  // weight prefetch prologue: slots 0..PD-1
  uint4 wld[36];
  #pragma unroll
  for (int u = 0; u < PD; ++u) wld[u] = wbase[u*64];

  asm volatile("s_waitcnt lgkmcnt(0)\n\ts_barrier" ::: "memory");  // hA visible
  __builtin_amdgcn_sched_barrier(0);

  #pragma unroll 1
  for (int t = 0; t < 30; ++t) {
    // A-fragments from hA
    unsigned long long av[12];
    #pragma unroll
    for (int ks = 0; ks < 12; ++ks) av[ks] = hA[ks*64 + lane];
    asm volatile("s_waitcnt lgkmcnt(0)\n\ts_barrier" ::: "memory"); // reads done
    __builtin_amdgcn_sched_barrier(0);

    floatx4 acc[6];
    #pragma unroll
    for (int s = 0; s < 6; ++s) acc[s] = (floatx4){0.f, 0.f, 0.f, 0.f};

    #pragma unroll
    for (int u = 0; u < 36; ++u) {
      const int un = (u + PD) % 36;        // compile-time; u>=36-PD loads next step
      wld[un] = wbase[un*64];
      #pragma unroll
      for (int p = 0; p < 2; ++p) {
        const int F = 2*u + p;
        const int c = F / 6, k = F - 6*c;
        const int s = c >> 1, kh = c & 1;
        const unsigned int lo = p ? wld[u].z : wld[u].x;
        const unsigned int hi = p ? wld[u].w : wld[u].y;
        const long bfrag = (long)(((unsigned long long)hi << 32) | lo);
        acc[s] = __builtin_amdgcn_mfma_f32_16x16x32_fp8_fp8(
            (long)av[kh*6 + k], bfrag, acc[s], 0, 0, 0);
      }
    }

    // ---- fused GRU epilogue (wave-local) ----
    #pragma unroll
    for (int half = 0; half < 2; ++half) {
      #pragma unroll
      for (int r = 0; r < 4; ++r) {
        const float ghr = acc[0 + half][r] + bb[0 + half];
        const float ghz = acc[2 + half][r] + bb[2 + half];
        const float ghn = acc[4 + half][r] + bb[4 + half];
        const float rg = 1.f/(1.f + __expf(-(gvv[r][0 + half] + ghr)));
        const float z  = 1.f/(1.f + __expf(-(gvv[r][2 + half] + ghz)));
        const float x2 = gvv[r][4 + half] + rg*ghn;
        const float nn = 2.f/(1.f + __expf(-2.f*x2)) - 1.f;   // tanh
        const float hold = hreg[half][r];
        const float hnew = (1.f - z)*nn + z*hold;
        hreg[half][r] = g0r[r]*hold + g1r[r]*hnew;
      }
    }

    // ---- new fp8 hA image + h dump slot t+1 ----
    #pragma unroll
    for (int half = 0; half < 2; ++half) {
      const int c = half ? c1 : c0;
      const int base = (c >> 5)*512 + ((c >> 3) & 3)*128 + (c & 7);
      half4_t hv;
      #pragma unroll
      for (int r = 0; r < 4; ++r) {
        __hip_fp8_e4m3 q(hreg[half][r]);
        ((unsigned char*)hA)[base + (kg*4 + r)*8] = q.__x;
        hv[r] = (_Float16)hreg[half][r];
      }
      *(half4_t*)&hdump[(((size_t)(t+1)*16 + bid)*384 + c)*16 + kg*4] = hv;
    }

    // ---- word-boundary loads for next word ----
    if (t % 3 == 2) {
      const int wi = (t/3 + 1 < 10) ? t/3 + 1 : 9;
      int4 wd4 = *(const int4*)&instr[(1+wi)*B_ + b0 + kg*4];
      wdr[0] = wd4.x; wdr[1] = wd4.y; wdr[2] = wd4.z; wdr[3] = wd4.w;
      #pragma unroll
      for (int r = 0; r < 4; ++r) {
        float2 gg = *(const float2*)&g01[((size_t)wi*B_ + b0 + kg*4 + r)*2];
        g0r[r] = gg.x; g1r[r] = gg.y;
      }
      #pragma unroll
      for (int r = 0; r < 4; ++r) {
        const float* gp = giv + (size_t)wdr[r]*H3_;
        #pragma unroll
        for (int g = 0; g < 3; ++g) {
          gvv[r][g*2]   = gp[g*384 + c0];
          gvv[r][g*2+1] = gp[g*384 + c1];
        }
      }
    }

    asm volatile("s_waitcnt lgkmcnt(0)\n\ts_barrier" ::: "memory"); // hA writes
    __builtin_amdgcn_sched_barrier(0);
  }
  asm volatile("s_waitcnt vmcnt(0) lgkmcnt(0)" ::: "memory");
}

// ---------------------------------------------------------------------------
// attnS: decoupled attention/S recurrence. One block per batch element.
// ---------------------------------------------------------------------------
__global__ __launch_bounds__(256) void attnS_kernel(
    const _Float16* __restrict__ hdump, const float* __restrict__ keys,
    const float* __restrict__ g01, float* __restrict__ S_buf)
{
  __shared__ float keysT[128][52];
  __shared__ float Sr[50][13];
  __shared__ float hrF[256];
  __shared__ float part[4][64];
  __shared__ float pL[64], wmL[64], nvs[12];

  const int b = blockIdx.x, g = b >> 4, bl = b & 15;
  const int tid = threadIdx.x, wv = tid >> 6, lane = tid & 63;

  for (int i = tid; i < 128*L_; i += 256) {
    int k = i / L_, l = i - k*L_;
    keysT[k][l] = keys[l*128 + k];
  }
  for (int i = tid; i < 550; i += 256) Sr[i/11][i%11] = ((i % 11) == 0) ? 1.f : 0.f;
  __syncthreads();

  for (int t = 0; t < 30; ++t) {
    const int widx = t / 3;
    hrF[tid] = (float)hdump[(((size_t)t*16 + g)*384 + 128 + tid)*16 + bl];
    __syncthreads();

    {
      const int ty = wv >> 1, kh = wv & 1;
      float s = 0.f;
      if (lane < L_) {
        #pragma unroll
        for (int k = 0; k < 64; ++k)
          s += hrF[ty*128 + kh*64 + k] * keysT[kh*64 + k][lane];
      }
      part[wv][lane] = s;
    }
    __syncthreads();

    if (wv == 0 || wv == 2) {
      const int ty = wv >> 1;
      float val = (lane < L_) ? part[ty*2][lane] + part[ty*2+1][lane] : -1e30f;
      float mx = val;
      #pragma unroll
      for (int off = 32; off; off >>= 1) mx = fmaxf(mx, __shfl_xor(mx, off));
      float e = (lane < L_) ? __expf(val - mx) : 0.f;
      float sm = e;
      #pragma unroll
      for (int off = 32; off; off >>= 1) sm += __shfl_xor(sm, off);
      if (lane < L_) {
        if (ty == 0) pL[lane] = e / sm; else wmL[lane] = e / sm;
      }
    }
    __syncthreads();

    if (tid < 11) {
      float rv = 0.f;
      #pragma unroll 5
      for (int l = 0; l < L_; ++l) rv += pL[l]*Sr[l][tid];
      const float g0 = g01[(widx*B_ + b)*2 + 0];
      const float g1 = g01[(widx*B_ + b)*2 + 1];
      nvs[tid] = g1*rv + ((tid == 1 + widx) ? g0 : 0.f);
    }
    __syncthreads();

    for (int i = tid; i < 550; i += 256) {
      const int l = i / 11, j = i - l*11;
      Sr[l][j] = wmL[l]*nvs[j] + (1.f - wmL[l])*Sr[l][j];
    }
    __syncthreads();
  }

  for (int i = tid; i < 550; i += 256) {
    const int l = i / 11, j = i - l*11;
    S_buf[(size_t)b*600 + l*12 + j] = Sr[l][j];
  }
}

// ---------------------------------------------------------------------------
// lse: per (b,l) log-sum-exp over the 1000-v reconstruction.
// ---------------------------------------------------------------------------
__global__ __launch_bounds__(512) void lse_kernel(
    const float* __restrict__ S_buf, const float* __restrict__ prim_emb,
    const float* __restrict__ iv_g, const int* __restrict__ instr,
    float* __restrict__ ls_buf)
{
  __shared__ float prim[10][1000];
  __shared__ float iv[1000];
  __shared__ float Sr[50][12];
  __shared__ int wds[10];

  const int b = blockIdx.x;
  const int tid = threadIdx.x;

  if (tid < 10) wds[tid] = instr[(1+tid)*B_ + b];
  for (int i = tid; i < 600; i += 512) Sr[i/12][i%12] = S_buf[(size_t)b*600 + i];
  __syncthreads();
  for (int wi = 0; wi < 10; ++wi) {
    const float4* __restrict__ src = (const float4*)(prim_emb + (size_t)wds[wi]*V_);
    for (int i = tid; i < 250; i += 512) ((float4*)prim[wi])[i] = src[i];
  }
  for (int i = tid; i < 250; i += 512) ((float4*)iv)[i] = ((const float4*)iv_g)[i];
  __syncthreads();

  const int wave = tid >> 6, lane = tid & 63;
  for (int l = wave; l < L_; l += 8) {
    float c0 = Sr[l][0];
    float cw[10];
    #pragma unroll
    for (int wi = 0; wi < 10; ++wi) cw[wi] = Sr[l][1+wi];
    float sv[16];
    float mx = -1e30f;
    #pragma unroll
    for (int j = 0; j < 16; ++j) {
      int v = lane + 64*j;
      float s = -1e30f;
      if (v < V_) {
        s = c0 * iv[v];
        #pragma unroll
        for (int wi = 0; wi < 10; ++wi) s += cw[wi]*prim[wi][v];
      }
      sv[j] = s;
      mx = fmaxf(mx, s);
    }
    #pragma unroll
    for (int off = 32; off; off >>= 1) mx = fmaxf(mx, __shfl_xor(mx, off));
    float se = 0.f;
    #pragma unroll
    for (int j = 0; j < 16; ++j) {
      int v = lane + 64*j;
      if (v < V_) se += __expf(sv[j] - mx);
    }
    #pragma unroll
    for (int off = 32; off; off >>= 1) se += __shfl_xor(se, off);
    if (lane == 0) ls_buf[b*L_ + l] = mx + __logf(se);
  }
}

// ---------------------------------------------------------------------------
// write: per (v-chunk of 125, b) block computes sv - lse, contiguous stores.
// ---------------------------------------------------------------------------
__global__ __launch_bounds__(256) void write_kernel(
    const float* __restrict__ S_buf, const float* __restrict__ prim_emb,
    const float* __restrict__ iv_g, const float* __restrict__ ls_buf,
    const int* __restrict__ instr, float* __restrict__ out)
{
  __shared__ float SrT[11][52];
  __shared__ float lss[52];
  __shared__ float primc[10][128];
  __shared__ float ivc[128];
  __shared__ int wds[10];

  const int cx = blockIdx.x;      // 0..7
  const int b  = blockIdx.y;      // 0..255
  const int v0 = cx * 125;
  const int tid = threadIdx.x;

  if (tid < 10) wds[tid] = instr[(1+tid)*B_ + b];
  if (tid < 50) lss[tid] = ls_buf[b*L_ + tid];
  for (int i = tid; i < 550; i += 256) {
    int l = i / 11, j = i - l*11;
    SrT[j][l] = S_buf[(size_t)b*600 + l*12 + j];
  }
  for (int i = tid; i < 125; i += 256) ivc[i] = iv_g[v0 + i];
  __syncthreads();
  for (int i = tid; i < 1250; i += 256) {
    int wi = i / 125, j = i - wi*125;
    primc[wi][j] = prim_emb[(size_t)wds[wi]*V_ + v0 + j];
  }
  __syncthreads();

  float* __restrict__ dst = out + (size_t)b*50000 + (size_t)v0*50;
  for (int e = tid; e < 125*50; e += 256) {
    const int v = e / 50, l = e - v*50;
    float s = SrT[0][l]*ivc[v];
    #pragma unroll
    for (int wi = 0; wi < 10; ++wi) s += SrT[1+wi][l]*primc[wi][v];
    dst[e] = s - lss[l];
  }
}

// ---------------------------------------------------------------------------
extern "C" void kernel_launch(void* const* d_in, const int* in_sizes, int n_in,
                              void* d_out, int out_size, void* d_ws, size_t ws_size,
                              hipStream_t stream)
{
  (void)in_sizes; (void)n_in; (void)out_size; (void)ws_size;
  const float* gate_emb = (const float*)d_in[0];
  const float* prog_emb = (const float*)d_in[1];
  const float* prim_emb = (const float*)d_in[2];
  const float* sk       = (const float*)d_in[3];
  const float* iv       = (const float*)d_in[4];
  const float* w_ih     = (const float*)d_in[5];
  const float* w_hh     = (const float*)d_in[6];
  const float* b_ih     = (const float*)d_in[7];
  const float* b_hh     = (const float*)d_in[8];
  const int*   instr    = (const int*)d_in[9];
  const int*   tacts    = (const int*)d_in[10];
  float* out = (float*)d_out;

  float* ws     = (float*)d_ws;
  float* S_buf  = ws;                          // 256*600 f32
  float* g01    = S_buf + B_*600;              // 5120 f32
  float* ls_buf = g01 + NW_*B_*2;              // 12800 f32
  float* giv    = ls_buf + B_*L_;              // 1,152,000 f32
  unsigned long long* whh8 = (unsigned long long*)(giv + (size_t)V_*H3_);  // 442368 B
  _Float16* wih_h  = (_Float16*)(whh8 + 55296);              // 1152*224 f16
  _Float16* prog_h = wih_h + (size_t)H3_*224;                // 200000 f16
  _Float16* hdump  = prog_h + (size_t)V_*P_;                 // 31*16*384*16 f16

  hipLaunchKernelGGL(prep_kernel, dim3(1024), dim3(256), 0, stream,
      gate_emb, prog_emb, w_ih, w_hh, instr, tacts,
      g01, (unsigned char*)whh8, wih_h, prog_h, out);

  hipLaunchKernelGGL(gi_gemm, dim3(63, 18), dim3(256), 0, stream,
      prog_h, wih_h, b_ih, giv);

  hipLaunchKernelGGL(steps_kernel, dim3(16), dim3(768), 0, stream,
      (const uint4*)whh8, giv, g01, sk, b_hh, instr, hdump);

  hipLaunchKernelGGL(attnS_kernel, dim3(256), dim3(256), 0, stream,
      hdump, sk, g01, S_buf);

  hipLaunchKernelGGL(lse_kernel, dim3(256), dim3(512), 0, stream,
      S_buf, prim_emb, iv, instr, ls_buf);

  hipLaunchKernelGGL(write_kernel, dim3(8, 256), dim3(256), 0, stream,
      S_buf, prim_emb, iv, ls_buf, instr, out);
}

// Round 8
// 419.088 us; speedup vs baseline: 1.2315x; 1.2315x over previous
//
#include <hip/hip_runtime.h>
#include <hip/hip_fp16.h>
#include <hip/hip_fp8.h>

#define B_ 256
#define V_ 1000
#define P_ 200
#define L_ 50
#define H_ 384
#define H3_ 1152
#define NW_ 10
#define OUT1_OFF 12800000

typedef _Float16 half8 __attribute__((ext_vector_type(8)));
typedef _Float16 half4_t __attribute__((ext_vector_type(4)));
typedef float floatx4 __attribute__((ext_vector_type(4)));

// ---------------------------------------------------------------------------
// prep: fp8 pair-packed w_hh (8-wave/54-unit layout), f16 gi operands,
// gate softmax, out1.
// byte i: e=i&7, p=(i>>3)&1, l=(i>>4)&63, q=i>>10 (=w*54+u)
//   F=2u+p; c=F/12; kc=F%12; g=c/3; j=c%3
//   row = g*384 + 48w + 16j + (l&15); col = kc*32 + (l>>4)*8 + e
// ---------------------------------------------------------------------------
__global__ __launch_bounds__(256) void prep_kernel(
    const float* __restrict__ gate_emb, const float* __restrict__ prog_emb,
    const float* __restrict__ w_ih, const float* __restrict__ w_hh,
    const int* __restrict__ instr, const int* __restrict__ tacts,
    float* __restrict__ g01, unsigned char* __restrict__ whh8,
    _Float16* __restrict__ wih_h, _Float16* __restrict__ prog_h,
    float* __restrict__ out)
{
  const int stride = gridDim.x * blockDim.x;
  const int tid = blockIdx.x * blockDim.x + threadIdx.x;

  for (int i = tid; i < H3_*H_; i += stride) {
    const int e = i & 7;
    const int p = (i >> 3) & 1;
    const int l = (i >> 4) & 63;
    const int q = i >> 10;
    const int u = q % 54, w = q / 54;
    const int F = 2*u + p;
    const int c = F / 12, kc = F - 12*c;
    const int g = c / 3, j = c - 3*g;
    const int row = g*384 + 48*w + 16*j + (l & 15);
    const int col = kc*32 + (l >> 4)*8 + e;
    __hip_fp8_e4m3 qv(w_hh[row*H_ + col]);
    whh8[i] = qv.__x;
  }
  for (int i = tid; i < H3_*224; i += stride) {
    int r = i / 224, c = i - r*224;
    wih_h[i] = (_Float16)(c < P_ ? w_ih[r*P_ + c] : 0.f);
  }
  for (int i = tid; i < V_*P_; i += stride) prog_h[i] = (_Float16)prog_emb[i];
  for (int i = tid; i < NW_*B_; i += stride) {
    int w = i / B_, b = i - w*B_;
    int word = instr[(1+w)*B_ + b];
    float e0 = gate_emb[word*2], e1 = gate_emb[word*2+1];
    float m = fmaxf(e0, e1);
    float a = __expf(e0-m), c = __expf(e1-m);
    float inv = 1.f/(a+c);
    g01[i*2] = a*inv; g01[i*2+1] = c*inv;
  }
  for (int i = tid; i < B_*L_; i += stride) {
    int b = i / L_, l = i - b*L_;
    out[OUT1_OFF + i] = (float)tacts[(1+l)*B_ + b];
  }
}

// ---------------------------------------------------------------------------
// gi_gemm: giv[v][n] = program_emb[v] @ w_ih.T + b_ih   (vocab-wide, once)
// ---------------------------------------------------------------------------
__global__ __launch_bounds__(256) void gi_gemm(
    const _Float16* __restrict__ prog_h, const _Float16* __restrict__ wih_h,
    const float* __restrict__ b_ih, float* __restrict__ giv)
{
  __shared__ _Float16 pA[16][232];
  const int tid = threadIdx.x;
  const int v0 = blockIdx.x * 16;
  const int n0 = blockIdx.y * 64;

  for (int i = tid; i < 16*224; i += 256) {
    int r = i / 224, c = i - r*224;
    int v = v0 + r;
    _Float16 val = (_Float16)0.f;
    if (v < V_ && c < P_) val = prog_h[v*P_ + c];
    pA[r][c] = val;
  }
  __syncthreads();

  const int wave = tid >> 6, lane = tid & 63;
  const int m = lane & 15, kg = lane >> 4;
  const int n_t = n0 + wave*16;
  floatx4 acc = {0.f, 0.f, 0.f, 0.f};
  #pragma unroll
  for (int ks = 0; ks < 7; ++ks) {
    const int kk = ks*32 + kg*8;
    half8 av = *(const half8*)&pA[m][kk];
    half8 bv = *(const half8*)&wih_h[(n_t + m)*224 + kk];
    acc = __builtin_amdgcn_mfma_f32_16x16x32_f16(av, bv, acc, 0, 0, 0);
  }
  const int nn = n_t + m;
  const float bias = b_ih[nn];
  #pragma unroll
  for (int r = 0; r < 4; ++r) {
    int mm = v0 + kg*4 + r;
    if (mm < V_) giv[(size_t)mm*H3_ + nn] = acc[r] + bias;
  }
}

// ---------------------------------------------------------------------------
// steps: GRU recurrence, 16 blocks x 512 threads (8 waves, 2/SIMD,
// 256-VGPR budget). Weights stream straight to NAMED registers w0..w8
// (9-stage rotation, 6 groups x 9 units, all indices compile-time).
// 54 dwordx4 loads/wave/step = 2 B-fragments each, consumed directly by
// MFMA. LDS = 6 KB fp8 h image only; 2 raw lgkm barriers/step.
// ---------------------------------------------------------------------------
__global__ __launch_bounds__(512, 2) void steps_kernel(
    const uint4* __restrict__ whh8p, const float* __restrict__ giv,
    const float* __restrict__ g01, const float* __restrict__ keys,
    const float* __restrict__ bhh, const int* __restrict__ instr,
    _Float16* __restrict__ hdump)
{
  __shared__ unsigned long long hA[768];   // fp8 h image [kc*64+lane]

  const int bid = blockIdx.x, b0 = bid*16, tid = threadIdx.x;
  const int w = tid >> 6, lane = tid & 63, m_ = lane & 15, kg = lane >> 4;

  const uint4* __restrict__ wbase = whh8p + (size_t)w*54*64 + lane;

  float hreg[3][4];            // [j][r]: col 48w+16j+m_, batch kg*4+r
  float bb[9];                 // [g*3+j]
  float gvv[4][9];             // [r][g*3+j]
  float g0r[4], g1r[4];
  int wdr[4];

  #pragma unroll
  for (int g = 0; g < 3; ++g)
    #pragma unroll
    for (int j = 0; j < 3; ++j)
      bb[g*3+j] = bhh[g*384 + 48*w + 16*j + m_];

  // h0 = tile(scratch_keys[0], 3)
  #pragma unroll
  for (int j = 0; j < 3; ++j) {
    const float h0 = keys[(48*w + 16*j + m_) & 127];
    #pragma unroll
    for (int r = 0; r < 4; ++r) hreg[j][r] = h0;
  }

  // initial fp8 hA image + h dump slot 0
  #pragma unroll
  for (int j = 0; j < 3; ++j) {
    const int c = 48*w + 16*j + m_;
    const int base = (c >> 5)*512 + ((c >> 3) & 3)*128 + (c & 7);
    half4_t hv;
    #pragma unroll
    for (int r = 0; r < 4; ++r) {
      __hip_fp8_e4m3 q(hreg[j][r]);
      ((unsigned char*)hA)[base + (kg*4 + r)*8] = q.__x;
      hv[r] = (_Float16)hreg[j][r];
    }
    *(half4_t*)&hdump[(((size_t)0*16 + bid)*384 + c)*16 + kg*4] = hv;
  }

  // word-0 parameter loads
  {
    int4 wd4 = *(const int4*)&instr[(1+0)*B_ + b0 + kg*4];
    wdr[0] = wd4.x; wdr[1] = wd4.y; wdr[2] = wd4.z; wdr[3] = wd4.w;
    #pragma unroll
    for (int r = 0; r < 4; ++r) {
      float2 gg = *(const float2*)&g01[(size_t)(b0 + kg*4 + r)*2];
      g0r[r] = gg.x; g1r[r] = gg.y;
    }
    #pragma unroll
    for (int r = 0; r < 4; ++r) {
      const float* gp = giv + (size_t)wdr[r]*H3_;
      #pragma unroll
      for (int g = 0; g < 3; ++g)
        #pragma unroll
        for (int j = 0; j < 3; ++j)
          gvv[r][g*3+j] = gp[g*384 + 48*w + 16*j + m_];
    }
  }

  // weight prefetch prologue: units 0..8 into named registers
  uint4 w0 = wbase[0*64], w1 = wbase[1*64], w2 = wbase[2*64];
  uint4 w3 = wbase[3*64], w4 = wbase[4*64], w5 = wbase[5*64];
  uint4 w6 = wbase[6*64], w7 = wbase[7*64], w8 = wbase[8*64];

  asm volatile("s_waitcnt lgkmcnt(0)\n\ts_barrier" ::: "memory");  // hA visible

#define LO64(W) ((long)((((unsigned long long)(W).y) << 32) | (W).x))
#define HI64(W) ((long)((((unsigned long long)(W).w) << 32) | (W).z))
#define UNIT(U, W) \
  { acc[(U)/6] = __builtin_amdgcn_mfma_f32_16x16x32_fp8_fp8( \
        (long)av[2*((U)%6)],   LO64(W), acc[(U)/6], 0, 0, 0); \
    acc[(U)/6] = __builtin_amdgcn_mfma_f32_16x16x32_fp8_fp8( \
        (long)av[2*((U)%6)+1], HI64(W), acc[(U)/6], 0, 0, 0); \
    W = wbase[(((U)+9)%54)*64]; }
#define GROUP(G) \
  UNIT((G)*9+0, w0) UNIT((G)*9+1, w1) UNIT((G)*9+2, w2) \
  UNIT((G)*9+3, w3) UNIT((G)*9+4, w4) UNIT((G)*9+5, w5) \
  UNIT((G)*9+6, w6) UNIT((G)*9+7, w7) UNIT((G)*9+8, w8)

  #pragma unroll 1
  for (int t = 0; t < 30; ++t) {
    // A-fragments from hA
    unsigned long long av[12];
    #pragma unroll
    for (int kc = 0; kc < 12; ++kc) av[kc] = hA[kc*64 + lane];
    asm volatile("s_waitcnt lgkmcnt(0)\n\ts_barrier" ::: "memory"); // reads done

    floatx4 acc[9];
    #pragma unroll
    for (int c = 0; c < 9; ++c) acc[c] = (floatx4){0.f, 0.f, 0.f, 0.f};

    GROUP(0) GROUP(1) GROUP(2) GROUP(3) GROUP(4) GROUP(5)

    // ---- fused GRU epilogue (wave-local) ----
    #pragma unroll
    for (int j = 0; j < 3; ++j) {
      #pragma unroll
      for (int r = 0; r < 4; ++r) {
        const float ghr = acc[j][r]   + bb[j];
        const float ghz = acc[3+j][r] + bb[3+j];
        const float ghn = acc[6+j][r] + bb[6+j];
        const float rg = 1.f/(1.f + __expf(-(gvv[r][j]   + ghr)));
        const float z  = 1.f/(1.f + __expf(-(gvv[r][3+j] + ghz)));
        const float x2 = gvv[r][6+j] + rg*ghn;
        const float nn = 2.f/(1.f + __expf(-2.f*x2)) - 1.f;   // tanh
        const float hold = hreg[j][r];
        const float hnew = (1.f - z)*nn + z*hold;
        hreg[j][r] = g0r[r]*hold + g1r[r]*hnew;
      }
    }

    // ---- new fp8 hA image + h dump slot t+1 ----
    #pragma unroll
    for (int j = 0; j < 3; ++j) {
      const int c = 48*w + 16*j + m_;
      const int base = (c >> 5)*512 + ((c >> 3) & 3)*128 + (c & 7);
      half4_t hv;
      #pragma unroll
      for (int r = 0; r < 4; ++r) {
        __hip_fp8_e4m3 q(hreg[j][r]);
        ((unsigned char*)hA)[base + (kg*4 + r)*8] = q.__x;
        hv[r] = (_Float16)hreg[j][r];
      }
      *(half4_t*)&hdump[(((size_t)(t+1)*16 + bid)*384 + c)*16 + kg*4] = hv;
    }

    // ---- word-boundary loads for next word ----
    if (t % 3 == 2) {
      const int wi = (t/3 + 1 < 10) ? t/3 + 1 : 9;
      int4 wd4 = *(const int4*)&instr[(1+wi)*B_ + b0 + kg*4];
      wdr[0] = wd4.x; wdr[1] = wd4.y; wdr[2] = wd4.z; wdr[3] = wd4.w;
      #pragma unroll
      for (int r = 0; r < 4; ++r) {
        float2 gg = *(const float2*)&g01[((size_t)wi*B_ + b0 + kg*4 + r)*2];
        g0r[r] = gg.x; g1r[r] = gg.y;
      }
      #pragma unroll
      for (int r = 0; r < 4; ++r) {
        const float* gp = giv + (size_t)wdr[r]*H3_;
        #pragma unroll
        for (int g = 0; g < 3; ++g)
          #pragma unroll
          for (int j = 0; j < 3; ++j)
            gvv[r][g*3+j] = gp[g*384 + 48*w + 16*j + m_];
      }
    }

    asm volatile("s_waitcnt lgkmcnt(0)\n\ts_barrier" ::: "memory"); // hA writes
  }
  asm volatile("s_waitcnt vmcnt(0) lgkmcnt(0)" ::: "memory");
#undef GROUP
#undef UNIT
#undef LO64
#undef HI64
}

// ---------------------------------------------------------------------------
// attnS: decoupled attention/S recurrence, one block per batch element.
// Phase 1: ALL 60 score rows (30 steps x {read,write}) computed in parallel
// from LDS-cached h/keys, softmax'd into sc[]. Phase 2: 30-step S recurrence
// (2 barriers/step, LDS only). No global traffic inside either loop.
// ---------------------------------------------------------------------------
__global__ __launch_bounds__(256) void attnS_kernel(
    const _Float16* __restrict__ hdump, const float* __restrict__ keys,
    const float* __restrict__ g01, float* __restrict__ S_buf)
{
  __shared__ float keysT[128][52];   // [k][l]
  __shared__ float hT[30][256];      // h cols 128..383 per step
  __shared__ float sc[30][2][52];    // softmax probs
  __shared__ float Sr[50][13];
  __shared__ float g0a[10], g1a[10];
  __shared__ float nvs[12];

  const int b = blockIdx.x, g = b >> 4, bl = b & 15;
  const int tid = threadIdx.x, wv = tid >> 6, lane = tid & 63;

  for (int i = tid; i < 128*L_; i += 256) {
    int k = i / L_, l = i - k*L_;
    keysT[k][l] = keys[l*128 + k];
  }
  for (int i = tid; i < 30*256; i += 256) {
    int t = i >> 8, c = i & 255;
    hT[t][c] = (float)hdump[(((size_t)t*16 + g)*384 + 128 + c)*16 + bl];
  }
  for (int i = tid; i < 550; i += 256) Sr[i/11][i%11] = ((i % 11) == 0) ? 1.f : 0.f;
  if (tid < NW_) {
    float2 gg = *(const float2*)&g01[((size_t)tid*B_ + b)*2];
    g0a[tid] = gg.x; g1a[tid] = gg.y;
  }
  __syncthreads();

  // ---- phase 1: 60 score rows, 15 per wave ----
  for (int row = wv; row < 60; row += 4) {
    const int t = row >> 1, ty = row & 1;
    float s = 0.f;
    if (lane < L_) {
      #pragma unroll 8
      for (int k = 0; k < 128; ++k)
        s += hT[t][ty*128 + k] * keysT[k][lane];
    }
    float val = (lane < L_) ? s : -1e30f;
    float mx = val;
    #pragma unroll
    for (int off = 32; off; off >>= 1) mx = fmaxf(mx, __shfl_xor(mx, off));
    float e = (lane < L_) ? __expf(val - mx) : 0.f;
    float sm = e;
    #pragma unroll
    for (int off = 32; off; off >>= 1) sm += __shfl_xor(sm, off);
    if (lane < L_) sc[t][ty][lane] = e / sm;
  }
  __syncthreads();

  // ---- phase 2: S recurrence ----
  for (int t = 0; t < 30; ++t) {
    const int widx = t / 3;
    if (tid < 11) {
      float rv = 0.f;
      #pragma unroll 5
      for (int l = 0; l < L_; ++l) rv += sc[t][0][l] * Sr[l][tid];
      nvs[tid] = g1a[widx]*rv + ((tid == 1 + widx) ? g0a[widx] : 0.f);
    }
    __syncthreads();
    for (int i = tid; i < 550; i += 256) {
      const int l = i / 11, j = i - l*11;
      const float wm = sc[t][1][l];
      Sr[l][j] = wm*nvs[j] + (1.f - wm)*Sr[l][j];
    }
    __syncthreads();
  }

  for (int i = tid; i < 550; i += 256) {
    const int l = i / 11, j = i - l*11;
    S_buf[(size_t)b*600 + l*12 + j] = Sr[l][j];
  }
}

// ---------------------------------------------------------------------------
// write (lse fused): per (v-chunk of 125, b) block. Full prim rows in LDS;
// lse computed in-block (redundant across cx, compute-cheap), then the
// 125x50 chunk is reconstructed and stored contiguously.
// ---------------------------------------------------------------------------
__global__ __launch_bounds__(256) void write_kernel(
    const float* __restrict__ S_buf, const float* __restrict__ prim_emb,
    const float* __restrict__ iv_g, const int* __restrict__ instr,
    float* __restrict__ out)
{
  __shared__ float prim[10][1000];
  __shared__ float iv[1000];
  __shared__ float SrT[11][52];
  __shared__ float lss[52];
  __shared__ int wds[10];

  const int cx = blockIdx.x;      // 0..7
  const int b  = blockIdx.y;      // 0..255
  const int v0 = cx * 125;
  const int tid = threadIdx.x;

  if (tid < 10) wds[tid] = instr[(1+tid)*B_ + b];
  for (int i = tid; i < 550; i += 256) {
    int l = i / 11, j = i - l*11;
    SrT[j][l] = S_buf[(size_t)b*600 + l*12 + j];
  }
  for (int i = tid; i < 250; i += 256) ((float4*)iv)[i] = ((const float4*)iv_g)[i];
  __syncthreads();
  for (int wi = 0; wi < 10; ++wi) {
    const float4* __restrict__ src = (const float4*)(prim_emb + (size_t)wds[wi]*V_);
    for (int i = tid; i < 250; i += 256) ((float4*)prim[wi])[i] = src[i];
  }
  __syncthreads();

  // lse per l (4 waves x rows)
  const int wv = tid >> 6, lane = tid & 63;
  for (int l = wv; l < L_; l += 4) {
    float c0 = SrT[0][l];
    float cw[10];
    #pragma unroll
    for (int wi = 0; wi < 10; ++wi) cw[wi] = SrT[1+wi][l];
    float sv[16];
    float mx = -1e30f;
    #pragma unroll
    for (int jj = 0; jj < 16; ++jj) {
      int v = lane + 64*jj;
      float s = -1e30f;
      if (v < V_) {
        s = c0 * iv[v];
        #pragma unroll
        for (int wi = 0; wi < 10; ++wi) s += cw[wi]*prim[wi][v];
      }
      sv[jj] = s;
      mx = fmaxf(mx, s);
    }
    #pragma unroll
    for (int off = 32; off; off >>= 1) mx = fmaxf(mx, __shfl_xor(mx, off));
    float se = 0.f;
    #pragma unroll
    for (int jj = 0; jj < 16; ++jj) {
      int v = lane + 64*jj;
      if (v < V_) se += __expf(sv[jj] - mx);
    }
    #pragma unroll
    for (int off = 32; off; off >>= 1) se += __shfl_xor(se, off);
    if (lane == 0) lss[l] = mx + __logf(se);
  }
  __syncthreads();

  float* __restrict__ dst = out + (size_t)b*50000 + (size_t)v0*50;
  for (int e = tid; e < 125*50; e += 256) {
    const int v = e / 50, l = e - v*50;
    const int vg = v0 + v;
    float s = SrT[0][l]*iv[vg];
    #pragma unroll
    for (int wi = 0; wi < 10; ++wi) s += SrT[1+wi][l]*prim[wi][vg];
    dst[e] = s - lss[l];
  }
}

// ---------------------------------------------------------------------------
extern "C" void kernel_launch(void* const* d_in, const int* in_sizes, int n_in,
                              void* d_out, int out_size, void* d_ws, size_t ws_size,
                              hipStream_t stream)
{
  (void)in_sizes; (void)n_in; (void)out_size; (void)ws_size;
  const float* gate_emb = (const float*)d_in[0];
  const float* prog_emb = (const float*)d_in[1];
  const float* prim_emb = (const float*)d_in[2];
  const float* sk       = (const float*)d_in[3];
  const float* iv       = (const float*)d_in[4];
  const float* w_ih     = (const float*)d_in[5];
  const float* w_hh     = (const float*)d_in[6];
  const float* b_ih     = (const float*)d_in[7];
  const float* b_hh     = (const float*)d_in[8];
  const int*   instr    = (const int*)d_in[9];
  const int*   tacts    = (const int*)d_in[10];
  float* out = (float*)d_out;

  float* ws     = (float*)d_ws;
  float* S_buf  = ws;                          // 256*600 f32
  float* g01    = S_buf + B_*600;              // 5120 f32
  float* giv    = g01 + NW_*B_*2;              // 1,152,000 f32
  unsigned long long* whh8 = (unsigned long long*)(giv + (size_t)V_*H3_);  // 442368 B
  _Float16* wih_h  = (_Float16*)(whh8 + 55296);              // 1152*224 f16
  _Float16* prog_h = wih_h + (size_t)H3_*224;                // 200000 f16
  _Float16* hdump  = prog_h + (size_t)V_*P_;                 // 31*16*384*16 f16

  hipLaunchKernelGGL(prep_kernel, dim3(1024), dim3(256), 0, stream,
      gate_emb, prog_emb, w_ih, w_hh, instr, tacts,
      g01, (unsigned char*)whh8, wih_h, prog_h, out);

  hipLaunchKernelGGL(gi_gemm, dim3(63, 18), dim3(256), 0, stream,
      prog_h, wih_h, b_ih, giv);

  hipLaunchKernelGGL(steps_kernel, dim3(16), dim3(512), 0, stream,
      (const uint4*)whh8, giv, g01, sk, b_hh, instr, hdump);

  hipLaunchKernelGGL(attnS_kernel, dim3(256), dim3(256), 0, stream,
      hdump, sk, g01, S_buf);

  hipLaunchKernelGGL(write_kernel, dim3(8, 256), dim3(256), 0, stream,
      S_buf, prim_emb, iv, instr, out);
}